// Round 5
// baseline (2483.152 us; speedup 1.0000x reference)
//
#include <hip/hip_runtime.h>
#include <cstdint>
#include <cstddef>

#define DIM 512
#define NLAYERS 3
#define GBM 128
#define GBN 128
#define GBK 64
#define SLABC 16              // columns per slab (3.2 MB working set -> fits 4 MiB XCD L2)
#define NSLAB (DIM / SLABC)   // 32
#define SLAB_PER_XCD (NSLAB / 8)  // 4

typedef float f32x4 __attribute__((ext_vector_type(4)));
typedef short bf16x8 __attribute__((ext_vector_type(8)));
typedef unsigned short u16x4 __attribute__((ext_vector_type(4)));
typedef unsigned short u16x8 __attribute__((ext_vector_type(8)));

__device__ __forceinline__ unsigned short f32_to_bf16(float f) {
    unsigned u = __float_as_uint(f);
    u += 0x7fffu + ((u >> 16) & 1u);
    return (unsigned short)(u >> 16);
}
__device__ __forceinline__ float bf16_to_f32(unsigned short h) {
    return __uint_as_float(((unsigned)h) << 16);
}

// async global->LDS, 16B per lane; LDS dest = wave-uniform base + lane*16
__device__ __forceinline__ void gl_lds16(const unsigned short* g, unsigned short* l) {
    __builtin_amdgcn_global_load_lds(
        (const __attribute__((address_space(1))) void*)g,
        (__attribute__((address_space(3))) void*)l,
        16, 0, 0);
}

// ---------------- CSR build ----------------
__global__ void csr_count(const int* __restrict__ ei, int* __restrict__ counts, int E) {
    int e = blockIdx.x * 256 + threadIdx.x;
    if (e < E) atomicAdd(&counts[ei[E + e]], 1);
}

__global__ void csr_scan(const int* __restrict__ counts, int* __restrict__ rowptr,
                         int* __restrict__ cursor, int N, int E) {
    __shared__ int sh[1024];
    int t = threadIdx.x;
    int chunk = (N + 1023) / 1024;
    int lo = t * chunk, hi = lo + chunk; if (hi > N) hi = N; if (lo > N) lo = N;
    int run = 0;
    for (int i = lo; i < hi; i++) { rowptr[i] = run; run += counts[i]; }
    sh[t] = run;
    __syncthreads();
    for (int d = 1; d < 1024; d <<= 1) {
        int v = (t >= d) ? sh[t - d] : 0;
        __syncthreads();
        sh[t] += v;
        __syncthreads();
    }
    int off = sh[t] - run;
    for (int i = lo; i < hi; i++) {
        int v = rowptr[i] + off;
        rowptr[i] = v; cursor[i] = v;
    }
    if (t == 0) rowptr[N] = E;
}

__global__ void csr_fill(const int* __restrict__ ei, int* __restrict__ cursor,
                         int* __restrict__ colsrc, int E) {
    int e = blockIdx.x * 256 + threadIdx.x;
    if (e < E) {
        int s = ei[e], d = ei[E + e];
        int p = atomicAdd(&cursor[d], 1);
        colsrc[p] = s;
    }
}

// ---------------- weight prep: W[l][k][n] fp32 -> Wt_hi/lo[mat][n][k] bf16 ----------------
__global__ void wprep(const float* __restrict__ W1, const float* __restrict__ W2,
                      unsigned short* __restrict__ Whi, unsigned short* __restrict__ Wlo) {
    int id = blockIdx.x * 256 + threadIdx.x;   // mat*65536 + k4*512 + n
    int mat = id >> 16;
    int k4 = (id >> 9) & 127;
    int n = id & 511;
    const float* W = (mat & 1) ? W2 : W1;
    const float* base = W + (size_t)(mat >> 1) * DIM * DIM;
    u16x4 h, l;
#pragma unroll
    for (int j = 0; j < 4; j++) {
        float v = base[(size_t)(k4 * 4 + j) * DIM + n];
        unsigned short hh = f32_to_bf16(v);
        h[j] = hh;
        l[j] = f32_to_bf16(v - bf16_to_f32(hh));
    }
    size_t o = ((size_t)mat * DIM + n) * DIM + k4 * 4;
    *reinterpret_cast<u16x4*>(Whi + o) = h;
    *reinterpret_cast<u16x4*>(Wlo + o) = l;
}

// ---------------- slab-partitioned aggregation -> bf16 hi/lo planes ----------------
// MODE 0: T = identity (layer 0, H = x).  MODE 1: T(v) = relu(relu(v*a2+c2)*a3+c3)
// One slab = 16 columns. Blocks with blockIdx%8 == x handle slabs [4x, 4x+3] so each
// XCD's gather working set is one 3.2 MB column slab (L2-resident). Correct under ANY
// block->XCD mapping; the %8 trick is locality-only.
template<int MODE>
__global__ void agg_slab(const float* __restrict__ H,
                         const int* __restrict__ rowptr, const int* __restrict__ colsrc,
                         const float* __restrict__ pa2, const float* __restrict__ pc2,
                         const float* __restrict__ pa3, const float* __restrict__ pc3,
                         unsigned short* __restrict__ Phi, unsigned short* __restrict__ Plo,
                         int N, int NB) {
    int b = blockIdx.x;
    int xcd = b & 7;
    int i = b >> 3;
    int si = i / NB;                 // 0..3  (slab within this XCD, long runs keep L2 warm)
    int ib = i - si * NB;
    int slab = xcd * SLAB_PER_XCD + si;
    int node = ib * 64 + (threadIdx.x >> 2);
    if (node >= N) return;
    int c = slab * SLABC + (threadIdx.x & 3) * 4;   // this thread's 4 columns

    f32x4 a2, c2, a3, c3;
    if (MODE) {
        a2 = *reinterpret_cast<const f32x4*>(pa2 + c);
        c2 = *reinterpret_cast<const f32x4*>(pc2 + c);
        a3 = *reinterpret_cast<const f32x4*>(pa3 + c);
        c3 = *reinterpret_cast<const f32x4*>(pc3 + c);
    }
    auto xf = [&](f32x4 v) -> f32x4 {
        if (MODE) {
#pragma unroll
            for (int j = 0; j < 4; j++) {
                float f = fmaxf(v[j] * a2[j] + c2[j], 0.f);
                v[j] = fmaxf(f * a3[j] + c3[j], 0.f);
            }
        }
        return v;
    };
    auto ld = [&](int r) -> f32x4 {
        return *reinterpret_cast<const f32x4*>(H + (size_t)r * DIM + c);
    };

    f32x4 acc = xf(ld(node));
    int e = rowptr[node], e1 = rowptr[node + 1];
    for (; e + 4 <= e1; e += 4) {
        int s0 = colsrc[e], s1 = colsrc[e + 1], s2 = colsrc[e + 2], s3 = colsrc[e + 3];
        f32x4 v0 = ld(s0);
        f32x4 v1 = ld(s1);
        f32x4 v2 = ld(s2);
        f32x4 v3 = ld(s3);
        acc += xf(v0); acc += xf(v1); acc += xf(v2); acc += xf(v3);
    }
    for (; e < e1; e++) acc += xf(ld(colsrc[e]));

    u16x4 h, l;
#pragma unroll
    for (int j = 0; j < 4; j++) {
        unsigned short hh = f32_to_bf16(acc[j]);
        h[j] = hh;
        l[j] = f32_to_bf16(acc[j] - bf16_to_f32(hh));
    }
    *reinterpret_cast<u16x4*>(Phi + (size_t)node * DIM + c) = h;
    *reinterpret_cast<u16x4*>(Plo + (size_t)node * DIM + c) = l;
}

// ---------------- convert: planes = split(relu(Y*a + c)) ----------------
__global__ void convert_kernel(const float* __restrict__ Y,
                               const float* __restrict__ pa, const float* __restrict__ pc,
                               unsigned short* __restrict__ Phi, unsigned short* __restrict__ Plo,
                               int total8) {
    int i = blockIdx.x * blockDim.x + threadIdx.x;
    int stride = gridDim.x * blockDim.x;
    for (; i < total8; i += stride) {
        int cb = (i & 63) * 8;
        f32x4 v0 = *reinterpret_cast<const f32x4*>(Y + (size_t)i * 8);
        f32x4 v1 = *reinterpret_cast<const f32x4*>(Y + (size_t)i * 8 + 4);
        f32x4 a0 = *reinterpret_cast<const f32x4*>(pa + cb);
        f32x4 a1 = *reinterpret_cast<const f32x4*>(pa + cb + 4);
        f32x4 c0 = *reinterpret_cast<const f32x4*>(pc + cb);
        f32x4 c1 = *reinterpret_cast<const f32x4*>(pc + cb + 4);
        u16x8 h, l;
#pragma unroll
        for (int j = 0; j < 4; j++) {
            float f = fmaxf(v0[j] * a0[j] + c0[j], 0.f);
            unsigned short hh = f32_to_bf16(f);
            h[j] = hh;
            l[j] = f32_to_bf16(f - bf16_to_f32(hh));
        }
#pragma unroll
        for (int j = 0; j < 4; j++) {
            float f = fmaxf(v1[j] * a1[j] + c1[j], 0.f);
            unsigned short hh = f32_to_bf16(f);
            h[4 + j] = hh;
            l[4 + j] = f32_to_bf16(f - bf16_to_f32(hh));
        }
        *reinterpret_cast<u16x8*>(Phi + (size_t)i * 8) = h;
        *reinterpret_cast<u16x8*>(Plo + (size_t)i * 8) = l;
    }
}

// ---------------- GEMM: Y = A @ W + bias from bf16 hi/lo planes, + column stats ----------
__global__ __launch_bounds__(256, 2)
void gemm_kernel(const unsigned short* __restrict__ Ahi,
                 const unsigned short* __restrict__ Alo,
                 const unsigned short* __restrict__ Bhi,
                 const unsigned short* __restrict__ Blo,
                 const float* __restrict__ bias,
                 float* __restrict__ Y,
                 float* __restrict__ ssum, float* __restrict__ ssq,
                 int M) {
    __shared__ unsigned short lds[4 * GBM * GBK];   // 64 KB
    unsigned short* sAhi = lds;
    unsigned short* sAlo = lds + GBM * GBK;
    unsigned short* sBhi = lds + 2 * GBM * GBK;
    unsigned short* sBlo = lds + 3 * GBM * GBK;

    const int tid = threadIdx.x;
    const int lane = tid & 63;
    const int wave = tid >> 6;
    const int wm = wave >> 1, wn = wave & 1;
    const int n0 = blockIdx.x * GBN;   // n-blocks fastest: 4 consecutive blocks share A panel
    const int m0 = blockIdx.y * GBM;

    const int lrow = lane >> 3;        // 0..7 within 8-row group
    const int lkc = (lane & 7) * 8;    // element col offset (8 bf16 = 16B)

    f32x4 acc[4][4];
#pragma unroll
    for (int i = 0; i < 4; i++)
#pragma unroll
        for (int j = 0; j < 4; j++) acc[i][j] = (f32x4){0.f, 0.f, 0.f, 0.f};

    for (int kt = 0; kt < DIM; kt += GBK) {
        __syncthreads();
#pragma unroll
        for (int i = 0; i < 4; i++) {
            int r = wave * 8 + i * 32 + lrow;                 // tile row 0..127
            int ldso = wave * 512 + i * 2048;                 // wave-uniform LDS elem offset
            size_t ga = (size_t)(m0 + r) * DIM + kt + lkc;
            size_t gb = (size_t)(n0 + r) * DIM + kt + lkc;
            gl_lds16(Ahi + ga, sAhi + ldso);
            gl_lds16(Alo + ga, sAlo + ldso);
            gl_lds16(Bhi + gb, sBhi + ldso);
            gl_lds16(Blo + gb, sBlo + ldso);
        }
        __syncthreads();
#pragma unroll
        for (int ks = 0; ks < 2; ks++) {
            const int kk = ks * 32 + (lane >> 4) * 8;
            const int ar = wm * 64 + (lane & 15);
            const int br = wn * 64 + (lane & 15);
            bf16x8 ah[4], al_[4], bh[4], bl[4];
#pragma unroll
            for (int f = 0; f < 4; f++) {
                ah[f]  = *reinterpret_cast<const bf16x8*>(&sAhi[(ar + f * 16) * GBK + kk]);
                al_[f] = *reinterpret_cast<const bf16x8*>(&sAlo[(ar + f * 16) * GBK + kk]);
                bh[f]  = *reinterpret_cast<const bf16x8*>(&sBhi[(br + f * 16) * GBK + kk]);
                bl[f]  = *reinterpret_cast<const bf16x8*>(&sBlo[(br + f * 16) * GBK + kk]);
            }
#pragma unroll
            for (int mf = 0; mf < 4; mf++)
#pragma unroll
                for (int nf = 0; nf < 4; nf++) {
                    acc[mf][nf] = __builtin_amdgcn_mfma_f32_16x16x32_bf16(al_[mf], bh[nf], acc[mf][nf], 0, 0, 0);
                    acc[mf][nf] = __builtin_amdgcn_mfma_f32_16x16x32_bf16(ah[mf], bl[nf], acc[mf][nf], 0, 0, 0);
                    acc[mf][nf] = __builtin_amdgcn_mfma_f32_16x16x32_bf16(ah[mf], bh[nf], acc[mf][nf], 0, 0, 0);
                }
        }
    }

    // epilogue: bias add, store, column stats
    const int ln16 = lane & 15;
    const int lg = lane >> 4;
#pragma unroll
    for (int nf = 0; nf < 4; nf++) {
        int col = n0 + wn * 64 + nf * 16 + ln16;
        float b = bias[col];
        float s = 0.f, q = 0.f;
#pragma unroll
        for (int mf = 0; mf < 4; mf++) {
#pragma unroll
            for (int r = 0; r < 4; r++) {
                int row = m0 + wm * 64 + mf * 16 + lg * 4 + r;
                if (row < M) {
                    float v = acc[mf][nf][r] + b;
                    Y[(size_t)row * DIM + col] = v;
                    s += v; q += v * v;
                }
            }
        }
        s += __shfl_xor(s, 16);
        s += __shfl_xor(s, 32);
        q += __shfl_xor(q, 16);
        q += __shfl_xor(q, 32);
        if (lg == 0) {
            atomicAdd(&ssum[col], s);
            atomicAdd(&ssq[col], q);
        }
    }
}

// ---------------- column stats of u = relu?(Y*a + c) ----------------
template<int RELU>
__global__ void ustats_kernel(const float* __restrict__ Y,
                              const float* __restrict__ pa, const float* __restrict__ pc,
                              float* __restrict__ ssum, float* __restrict__ ssq,
                              int M, int chunk) {
    int d = blockIdx.x * blockDim.x + threadIdx.x;
    int r0 = blockIdx.y * chunk;
    int r1 = r0 + chunk; if (r1 > M) r1 = M;
    float a = pa[d], c = pc[d];
    float s = 0.f, q = 0.f;
    for (int r = r0; r < r1; r++) {
        float v = Y[(size_t)r * DIM + d] * a + c;
        if (RELU) v = fmaxf(v, 0.f);
        s += v; q += v * v;
    }
    atomicAdd(&ssum[d], s);
    atomicAdd(&ssq[d], q);
}

// ---------------- BN params: a = g*rsqrt(var+eps), c = beta - mean*a ----------------
__global__ void params_kernel(const float* __restrict__ ssum, const float* __restrict__ ssq,
                              const float* __restrict__ g, const float* __restrict__ b,
                              float* __restrict__ pa, float* __restrict__ pc, float invN) {
    int d = threadIdx.x + blockIdx.x * blockDim.x;
    float m = ssum[d] * invN;
    float var = ssq[d] * invN - m * m;
    var = fmaxf(var, 0.f);
    float s = rsqrtf(var + 1e-5f);
    float a = g[d] * s;
    pa[d] = a;
    pc[d] = b[d] - m * a;
}

// ---------------- final in-place: out = (out*a2+c2)*a3+c3 ----------------
__global__ void finalize_kernel(float* __restrict__ Y,
                                const float* __restrict__ pa2, const float* __restrict__ pc2,
                                const float* __restrict__ pa3, const float* __restrict__ pc3,
                                int total4) {
    int i = blockIdx.x * blockDim.x + threadIdx.x;
    int stride = gridDim.x * blockDim.x;
    for (; i < total4; i += stride) {
        int c = (i & 127) * 4;
        f32x4 v = *reinterpret_cast<f32x4*>(Y + (size_t)i * 4);
#pragma unroll
        for (int j = 0; j < 4; j++) {
            float f = v[j] * pa2[c + j] + pc2[c + j];
            v[j] = f * pa3[c + j] + pc3[c + j];
        }
        *reinterpret_cast<f32x4*>(Y + (size_t)i * 4) = v;
    }
}

extern "C" void kernel_launch(void* const* d_in, const int* in_sizes, int n_in,
                              void* d_out, int out_size, void* d_ws, size_t ws_size,
                              hipStream_t stream) {
    const float* x   = (const float*)d_in[0];
    const int*   ei  = (const int*)d_in[1];
    const float* W1  = (const float*)d_in[2];
    const float* b1  = (const float*)d_in[3];
    const float* g1  = (const float*)d_in[4];
    const float* be1 = (const float*)d_in[5];
    const float* W2  = (const float*)d_in[6];
    const float* b2  = (const float*)d_in[7];
    const float* g2  = (const float*)d_in[8];
    const float* be2 = (const float*)d_in[9];
    const float* ng  = (const float*)d_in[10];
    const float* nb  = (const float*)d_in[11];

    const int N = in_sizes[0] / DIM;
    const int E = in_sizes[1] / 2;

    char* ws = (char*)d_ws;
    size_t off = 0;
    auto alloc = [&](size_t bytes) -> void* {
        void* p = ws + off;
        off += (bytes + 255) & ~(size_t)255;
        return p;
    };
    unsigned short* Phi = (unsigned short*)alloc((size_t)N * DIM * 2);
    unsigned short* Plo = (unsigned short*)alloc((size_t)N * DIM * 2);
    float* y1 = (float*)alloc((size_t)N * DIM * 4);
    unsigned short* Whi = (unsigned short*)alloc(6ull * DIM * DIM * 2);
    unsigned short* Wlo = (unsigned short*)alloc(6ull * DIM * DIM * 2);
    int* rowptr = (int*)alloc((size_t)(N + 1) * 4);
    int* counts = (int*)alloc((size_t)N * 4);
    int* cursor = (int*)alloc((size_t)N * 4);
    int* colsrc = (int*)alloc((size_t)E * 4);
    float* stats = (float*)alloc(9ull * 1024 * 4);
    float* prm = (float*)alloc(6ull * DIM * 4);

    float* Yout = (float*)d_out;
    float* pa1 = prm,         *pc1 = prm + DIM;
    float* pa2 = prm + 2*DIM, *pc2 = prm + 3*DIM;
    float* pa3 = prm + 4*DIM, *pc3 = prm + 5*DIM;

    hipMemsetAsync(counts, 0, (size_t)N * 4, stream);
    hipMemsetAsync(stats, 0, 9ull * 1024 * 4, stream);

    wprep<<<1536, 256, 0, stream>>>(W1, W2, Whi, Wlo);
    csr_count<<<(E + 255) / 256, 256, 0, stream>>>(ei, counts, E);
    csr_scan<<<1, 1024, 0, stream>>>(counts, rowptr, cursor, N, E);
    csr_fill<<<(E + 255) / 256, 256, 0, stream>>>(ei, cursor, colsrc, E);

    const float invN = 1.0f / (float)N;
    dim3 ggrid(DIM / GBN, (N + GBM - 1) / GBM);
    const int uchunk = (N + 199) / 200;
    const int total8 = N * DIM / 8;
    const int NB = (N + 63) / 64;                 // node-blocks per slab
    const int agg_grid = 8 * SLAB_PER_XCD * NB;   // xcd-major: b&7 selects XCD

    for (int l = 0; l < NLAYERS; l++) {
        float* st1 = stats + (size_t)l * 3 * 1024;
        float* st2 = st1 + 1024;
        float* st3 = st2 + 1024;
        if (l == 0)
            agg_slab<0><<<agg_grid, 256, 0, stream>>>(x, rowptr, colsrc,
                                                      nullptr, nullptr, nullptr, nullptr,
                                                      Phi, Plo, N, NB);
        else
            agg_slab<1><<<agg_grid, 256, 0, stream>>>(Yout, rowptr, colsrc,
                                                      pa2, pc2, pa3, pc3, Phi, Plo, N, NB);
        gemm_kernel<<<ggrid, 256, 0, stream>>>(Phi, Plo,
            Whi + (size_t)(l * 2) * DIM * DIM, Wlo + (size_t)(l * 2) * DIM * DIM,
            b1 + l * DIM, y1, st1, st1 + 512, N);
        params_kernel<<<1, 512, 0, stream>>>(st1, st1 + 512, g1 + l * DIM, be1 + l * DIM,
                                             pa1, pc1, invN);
        convert_kernel<<<2048, 256, 0, stream>>>(y1, pa1, pc1, Phi, Plo, total8);
        gemm_kernel<<<ggrid, 256, 0, stream>>>(Phi, Plo,
            Whi + (size_t)(l * 2 + 1) * DIM * DIM, Wlo + (size_t)(l * 2 + 1) * DIM * DIM,
            b2 + l * DIM, Yout, st2, st2 + 512, N);
        params_kernel<<<1, 512, 0, stream>>>(st2, st2 + 512, g2 + l * DIM, be2 + l * DIM,
                                             pa2, pc2, invN);
        if (l < NLAYERS - 1)
            ustats_kernel<1><<<dim3(2, 200), 256, 0, stream>>>(Yout, pa2, pc2,
                                                               st3, st3 + 512, N, uchunk);
        else
            ustats_kernel<0><<<dim3(2, 200), 256, 0, stream>>>(Yout, pa2, pc2,
                                                               st3, st3 + 512, N, uchunk);
        params_kernel<<<1, 512, 0, stream>>>(st3, st3 + 512, ng + l * DIM, nb + l * DIM,
                                             pa3, pc3, invN);
    }
    finalize_kernel<<<2048, 256, 0, stream>>>(Yout, pa2, pc2, pa3, pc3, N * DIM / 4);
}

// Round 6
// 2225.155 us; speedup vs baseline: 1.1159x; 1.1159x over previous
//
#include <hip/hip_runtime.h>
#include <cstdint>
#include <cstddef>

#define DIM 512
#define NLAYERS 3
#define GBM 128
#define GBN 128
#define GBK 64

typedef float f32x4 __attribute__((ext_vector_type(4)));
typedef short bf16x8 __attribute__((ext_vector_type(8)));
typedef unsigned short u16x4 __attribute__((ext_vector_type(4)));
typedef unsigned short u16x8 __attribute__((ext_vector_type(8)));

__device__ __forceinline__ unsigned short f32_to_bf16(float f) {
    unsigned u = __float_as_uint(f);
    u += 0x7fffu + ((u >> 16) & 1u);
    return (unsigned short)(u >> 16);
}
__device__ __forceinline__ float bf16_to_f32(unsigned short h) {
    return __uint_as_float(((unsigned)h) << 16);
}

// async global->LDS, 16B per lane; LDS dest = wave-uniform base + lane*16
__device__ __forceinline__ void gl_lds16(const unsigned short* g, unsigned short* l) {
    __builtin_amdgcn_global_load_lds(
        (const __attribute__((address_space(1))) void*)g,
        (__attribute__((address_space(3))) void*)l,
        16, 0, 0);
}

// ---------------- CSR build ----------------
__global__ void csr_count(const int* __restrict__ ei, int* __restrict__ counts, int E) {
    int e = blockIdx.x * 256 + threadIdx.x;
    if (e < E) atomicAdd(&counts[ei[E + e]], 1);
}

__global__ void csr_scan(const int* __restrict__ counts, int* __restrict__ rowptr,
                         int* __restrict__ cursor, int N, int E) {
    __shared__ int sh[1024];
    int t = threadIdx.x;
    int chunk = (N + 1023) / 1024;
    int lo = t * chunk, hi = lo + chunk; if (hi > N) hi = N; if (lo > N) lo = N;
    int run = 0;
    for (int i = lo; i < hi; i++) { rowptr[i] = run; run += counts[i]; }
    sh[t] = run;
    __syncthreads();
    for (int d = 1; d < 1024; d <<= 1) {
        int v = (t >= d) ? sh[t - d] : 0;
        __syncthreads();
        sh[t] += v;
        __syncthreads();
    }
    int off = sh[t] - run;
    for (int i = lo; i < hi; i++) {
        int v = rowptr[i] + off;
        rowptr[i] = v; cursor[i] = v;
    }
    if (t == 0) rowptr[N] = E;
}

__global__ void csr_fill(const int* __restrict__ ei, int* __restrict__ cursor,
                         int* __restrict__ colsrc, int E) {
    int e = blockIdx.x * 256 + threadIdx.x;
    if (e < E) {
        int s = ei[e], d = ei[E + e];
        int p = atomicAdd(&cursor[d], 1);
        colsrc[p] = s;
    }
}

// ---------------- weight prep: W[l][k][n] fp32 -> Wt_hi/lo[mat][n][k] bf16 ----------------
__global__ void wprep(const float* __restrict__ W1, const float* __restrict__ W2,
                      unsigned short* __restrict__ Whi, unsigned short* __restrict__ Wlo) {
    int id = blockIdx.x * 256 + threadIdx.x;   // mat*65536 + k4*512 + n
    int mat = id >> 16;
    int k4 = (id >> 9) & 127;
    int n = id & 511;
    const float* W = (mat & 1) ? W2 : W1;
    const float* base = W + (size_t)(mat >> 1) * DIM * DIM;
    u16x4 h, l;
#pragma unroll
    for (int j = 0; j < 4; j++) {
        float v = base[(size_t)(k4 * 4 + j) * DIM + n];
        unsigned short hh = f32_to_bf16(v);
        h[j] = hh;
        l[j] = f32_to_bf16(v - bf16_to_f32(hh));
    }
    size_t o = ((size_t)mat * DIM + n) * DIM + k4 * 4;
    *reinterpret_cast<u16x4*>(Whi + o) = h;
    *reinterpret_cast<u16x4*>(Wlo + o) = l;
}

// ---------------- aggregation -> bf16 hi/lo planes (row-per-block; R3 form) ----------------
// MODE 0: T = identity (layer 0, H = x).  MODE 1: T(v) = relu(relu(v*a2+c2)*a3+c3)
template<int MODE>
__global__ void agg_kernel(const float* __restrict__ H,
                           const int* __restrict__ rowptr, const int* __restrict__ colsrc,
                           const float* __restrict__ pa2, const float* __restrict__ pc2,
                           const float* __restrict__ pa3, const float* __restrict__ pc3,
                           unsigned short* __restrict__ Phi, unsigned short* __restrict__ Plo,
                           int N) {
    int n = blockIdx.x;
    int c = threadIdx.x * 4;   // 128 threads * float4 = 512 cols
    f32x4 a2, c2, a3, c3;
    if (MODE) {
        a2 = *reinterpret_cast<const f32x4*>(pa2 + c);
        c2 = *reinterpret_cast<const f32x4*>(pc2 + c);
        a3 = *reinterpret_cast<const f32x4*>(pa3 + c);
        c3 = *reinterpret_cast<const f32x4*>(pc3 + c);
    }
    auto xf = [&](f32x4 v) -> f32x4 {
        if (MODE) {
#pragma unroll
            for (int j = 0; j < 4; j++) {
                float f = fmaxf(v[j] * a2[j] + c2[j], 0.f);
                v[j] = fmaxf(f * a3[j] + c3[j], 0.f);
            }
        }
        return v;
    };
    auto ld = [&](int r) -> f32x4 {
        return *reinterpret_cast<const f32x4*>(H + (size_t)r * DIM + c);
    };
    f32x4 acc = xf(ld(n));
    int e0 = rowptr[n], e1 = rowptr[n + 1];
    int e = e0;
    for (; e + 4 <= e1; e += 4) {
        int s0 = colsrc[e], s1 = colsrc[e + 1], s2 = colsrc[e + 2], s3 = colsrc[e + 3];
        f32x4 v0 = ld(s0);
        f32x4 v1 = ld(s1);
        f32x4 v2 = ld(s2);
        f32x4 v3 = ld(s3);
        acc += xf(v0); acc += xf(v1); acc += xf(v2); acc += xf(v3);
    }
    for (; e < e1; e++) acc += xf(ld(colsrc[e]));
    u16x4 h, l;
#pragma unroll
    for (int j = 0; j < 4; j++) {
        unsigned short hh = f32_to_bf16(acc[j]);
        h[j] = hh;
        l[j] = f32_to_bf16(acc[j] - bf16_to_f32(hh));
    }
    *reinterpret_cast<u16x4*>(Phi + (size_t)n * DIM + c) = h;
    *reinterpret_cast<u16x4*>(Plo + (size_t)n * DIM + c) = l;
}

// ---------------- convert: planes = split(relu(Y*a + c)) ----------------
__global__ void convert_kernel(const float* __restrict__ Y,
                               const float* __restrict__ pa, const float* __restrict__ pc,
                               unsigned short* __restrict__ Phi, unsigned short* __restrict__ Plo,
                               int total8) {
    int i = blockIdx.x * blockDim.x + threadIdx.x;
    int stride = gridDim.x * blockDim.x;
    for (; i < total8; i += stride) {
        int cb = (i & 63) * 8;
        f32x4 v0 = *reinterpret_cast<const f32x4*>(Y + (size_t)i * 8);
        f32x4 v1 = *reinterpret_cast<const f32x4*>(Y + (size_t)i * 8 + 4);
        f32x4 a0 = *reinterpret_cast<const f32x4*>(pa + cb);
        f32x4 a1 = *reinterpret_cast<const f32x4*>(pa + cb + 4);
        f32x4 c0 = *reinterpret_cast<const f32x4*>(pc + cb);
        f32x4 c1 = *reinterpret_cast<const f32x4*>(pc + cb + 4);
        u16x8 h, l;
#pragma unroll
        for (int j = 0; j < 4; j++) {
            float f = fmaxf(v0[j] * a0[j] + c0[j], 0.f);
            unsigned short hh = f32_to_bf16(f);
            h[j] = hh;
            l[j] = f32_to_bf16(f - bf16_to_f32(hh));
        }
#pragma unroll
        for (int j = 0; j < 4; j++) {
            float f = fmaxf(v1[j] * a1[j] + c1[j], 0.f);
            unsigned short hh = f32_to_bf16(f);
            h[4 + j] = hh;
            l[4 + j] = f32_to_bf16(f - bf16_to_f32(hh));
        }
        *reinterpret_cast<u16x8*>(Phi + (size_t)i * 8) = h;
        *reinterpret_cast<u16x8*>(Plo + (size_t)i * 8) = l;
    }
}

// ---------------- GEMM: Y = A @ W + bias from bf16 hi/lo planes, + column stats ----------
// XCD-swizzled 1D grid: all 4 n-blocks of one m-panel land on the SAME XCD
// (dispatch-adjacent, b = base, base+8, base+16, base+24) so the 256 KB A panel
// is fetched from L3 once and re-served from that XCD's L2.
__global__ __launch_bounds__(256, 2)
void gemm_kernel(const unsigned short* __restrict__ Ahi,
                 const unsigned short* __restrict__ Alo,
                 const unsigned short* __restrict__ Bhi,
                 const unsigned short* __restrict__ Blo,
                 const float* __restrict__ bias,
                 float* __restrict__ Y,
                 float* __restrict__ ssum, float* __restrict__ ssq,
                 int M) {
    __shared__ unsigned short lds[4 * GBM * GBK];   // 64 KB
    unsigned short* sAhi = lds;
    unsigned short* sAlo = lds + GBM * GBK;
    unsigned short* sBhi = lds + 2 * GBM * GBK;
    unsigned short* sBlo = lds + 3 * GBM * GBK;

    const int tid = threadIdx.x;
    const int lane = tid & 63;
    const int wave = tid >> 6;
    const int wm = wave >> 1, wn = wave & 1;

    // bijective swizzle: b -> (g = m-panel, j = n-block), g%8 == b%8 (same XCD)
    const int b = blockIdx.x;
    const int xcd = b & 7;
    const int slot = b >> 3;
    const int g = (slot >> 2) * 8 + xcd;
    const int j = slot & 3;
    const int m0 = g * GBM;
    const int n0 = j * GBN;

    const int lrow = lane >> 3;        // 0..7 within 8-row group
    const int lkc = (lane & 7) * 8;    // element col offset (8 bf16 = 16B)

    f32x4 acc[4][4];
#pragma unroll
    for (int i = 0; i < 4; i++)
#pragma unroll
        for (int jj = 0; jj < 4; jj++) acc[i][jj] = (f32x4){0.f, 0.f, 0.f, 0.f};

    for (int kt = 0; kt < DIM; kt += GBK) {
        __syncthreads();
#pragma unroll
        for (int i = 0; i < 4; i++) {
            int r = wave * 8 + i * 32 + lrow;                 // tile row 0..127
            int ldso = wave * 512 + i * 2048;                 // wave-uniform LDS elem offset
            size_t ga = (size_t)(m0 + r) * DIM + kt + lkc;
            size_t gb = (size_t)(n0 + r) * DIM + kt + lkc;
            gl_lds16(Ahi + ga, sAhi + ldso);
            gl_lds16(Alo + ga, sAlo + ldso);
            gl_lds16(Bhi + gb, sBhi + ldso);
            gl_lds16(Blo + gb, sBlo + ldso);
        }
        __syncthreads();
#pragma unroll
        for (int ks = 0; ks < 2; ks++) {
            const int kk = ks * 32 + (lane >> 4) * 8;
            const int ar = wm * 64 + (lane & 15);
            const int br = wn * 64 + (lane & 15);
            bf16x8 ah[4], al_[4], bh[4], bl[4];
#pragma unroll
            for (int f = 0; f < 4; f++) {
                ah[f]  = *reinterpret_cast<const bf16x8*>(&sAhi[(ar + f * 16) * GBK + kk]);
                al_[f] = *reinterpret_cast<const bf16x8*>(&sAlo[(ar + f * 16) * GBK + kk]);
                bh[f]  = *reinterpret_cast<const bf16x8*>(&sBhi[(br + f * 16) * GBK + kk]);
                bl[f]  = *reinterpret_cast<const bf16x8*>(&sBlo[(br + f * 16) * GBK + kk]);
            }
#pragma unroll
            for (int mf = 0; mf < 4; mf++)
#pragma unroll
                for (int nf = 0; nf < 4; nf++) {
                    acc[mf][nf] = __builtin_amdgcn_mfma_f32_16x16x32_bf16(al_[mf], bh[nf], acc[mf][nf], 0, 0, 0);
                    acc[mf][nf] = __builtin_amdgcn_mfma_f32_16x16x32_bf16(ah[mf], bl[nf], acc[mf][nf], 0, 0, 0);
                    acc[mf][nf] = __builtin_amdgcn_mfma_f32_16x16x32_bf16(ah[mf], bh[nf], acc[mf][nf], 0, 0, 0);
                }
        }
    }

    // epilogue: bias add, store, column stats
    const int ln16 = lane & 15;
    const int lg = lane >> 4;
#pragma unroll
    for (int nf = 0; nf < 4; nf++) {
        int col = n0 + wn * 64 + nf * 16 + ln16;
        float bv = bias[col];
        float s = 0.f, q = 0.f;
#pragma unroll
        for (int mf = 0; mf < 4; mf++) {
#pragma unroll
            for (int r = 0; r < 4; r++) {
                int row = m0 + wm * 64 + mf * 16 + lg * 4 + r;
                if (row < M) {
                    float v = acc[mf][nf][r] + bv;
                    Y[(size_t)row * DIM + col] = v;
                    s += v; q += v * v;
                }
            }
        }
        s += __shfl_xor(s, 16);
        s += __shfl_xor(s, 32);
        q += __shfl_xor(q, 16);
        q += __shfl_xor(q, 32);
        if (lg == 0) {
            atomicAdd(&ssum[col], s);
            atomicAdd(&ssq[col], q);
        }
    }
}

// ---------------- column stats of u = relu?(Y*a + c) ----------------
template<int RELU>
__global__ void ustats_kernel(const float* __restrict__ Y,
                              const float* __restrict__ pa, const float* __restrict__ pc,
                              float* __restrict__ ssum, float* __restrict__ ssq,
                              int M, int chunk) {
    int d = blockIdx.x * blockDim.x + threadIdx.x;
    int r0 = blockIdx.y * chunk;
    int r1 = r0 + chunk; if (r1 > M) r1 = M;
    float a = pa[d], c = pc[d];
    float s = 0.f, q = 0.f;
    for (int r = r0; r < r1; r++) {
        float v = Y[(size_t)r * DIM + d] * a + c;
        if (RELU) v = fmaxf(v, 0.f);
        s += v; q += v * v;
    }
    atomicAdd(&ssum[d], s);
    atomicAdd(&ssq[d], q);
}

// ---------------- BN params: a = g*rsqrt(var+eps), c = beta - mean*a ----------------
__global__ void params_kernel(const float* __restrict__ ssum, const float* __restrict__ ssq,
                              const float* __restrict__ g, const float* __restrict__ b,
                              float* __restrict__ pa, float* __restrict__ pc, float invN) {
    int d = threadIdx.x + blockIdx.x * blockDim.x;
    float m = ssum[d] * invN;
    float var = ssq[d] * invN - m * m;
    var = fmaxf(var, 0.f);
    float s = rsqrtf(var + 1e-5f);
    float a = g[d] * s;
    pa[d] = a;
    pc[d] = b[d] - m * a;
}

// ---------------- final in-place: out = (out*a2+c2)*a3+c3 ----------------
__global__ void finalize_kernel(float* __restrict__ Y,
                                const float* __restrict__ pa2, const float* __restrict__ pc2,
                                const float* __restrict__ pa3, const float* __restrict__ pc3,
                                int total4) {
    int i = blockIdx.x * blockDim.x + threadIdx.x;
    int stride = gridDim.x * blockDim.x;
    for (; i < total4; i += stride) {
        int c = (i & 127) * 4;
        f32x4 v = *reinterpret_cast<f32x4*>(Y + (size_t)i * 4);
#pragma unroll
        for (int j = 0; j < 4; j++) {
            float f = v[j] * pa2[c + j] + pc2[c + j];
            v[j] = f * pa3[c + j] + pc3[c + j];
        }
        *reinterpret_cast<f32x4*>(Y + (size_t)i * 4) = v;
    }
}

extern "C" void kernel_launch(void* const* d_in, const int* in_sizes, int n_in,
                              void* d_out, int out_size, void* d_ws, size_t ws_size,
                              hipStream_t stream) {
    const float* x   = (const float*)d_in[0];
    const int*   ei  = (const int*)d_in[1];
    const float* W1  = (const float*)d_in[2];
    const float* b1  = (const float*)d_in[3];
    const float* g1  = (const float*)d_in[4];
    const float* be1 = (const float*)d_in[5];
    const float* W2  = (const float*)d_in[6];
    const float* b2  = (const float*)d_in[7];
    const float* g2  = (const float*)d_in[8];
    const float* be2 = (const float*)d_in[9];
    const float* ng  = (const float*)d_in[10];
    const float* nb  = (const float*)d_in[11];

    const int N = in_sizes[0] / DIM;
    const int E = in_sizes[1] / 2;

    char* ws = (char*)d_ws;
    size_t off = 0;
    auto alloc = [&](size_t bytes) -> void* {
        void* p = ws + off;
        off += (bytes + 255) & ~(size_t)255;
        return p;
    };
    unsigned short* Phi = (unsigned short*)alloc((size_t)N * DIM * 2);
    unsigned short* Plo = (unsigned short*)alloc((size_t)N * DIM * 2);
    float* y1 = (float*)alloc((size_t)N * DIM * 4);
    unsigned short* Whi = (unsigned short*)alloc(6ull * DIM * DIM * 2);
    unsigned short* Wlo = (unsigned short*)alloc(6ull * DIM * DIM * 2);
    int* rowptr = (int*)alloc((size_t)(N + 1) * 4);
    int* counts = (int*)alloc((size_t)N * 4);
    int* cursor = (int*)alloc((size_t)N * 4);
    int* colsrc = (int*)alloc((size_t)E * 4);
    float* stats = (float*)alloc(9ull * 1024 * 4);
    float* prm = (float*)alloc(6ull * DIM * 4);

    float* Yout = (float*)d_out;
    float* pa1 = prm,         *pc1 = prm + DIM;
    float* pa2 = prm + 2*DIM, *pc2 = prm + 3*DIM;
    float* pa3 = prm + 4*DIM, *pc3 = prm + 5*DIM;

    hipMemsetAsync(counts, 0, (size_t)N * 4, stream);
    hipMemsetAsync(stats, 0, 9ull * 1024 * 4, stream);

    wprep<<<1536, 256, 0, stream>>>(W1, W2, Whi, Wlo);
    csr_count<<<(E + 255) / 256, 256, 0, stream>>>(ei, counts, E);
    csr_scan<<<1, 1024, 0, stream>>>(counts, rowptr, cursor, N, E);
    csr_fill<<<(E + 255) / 256, 256, 0, stream>>>(ei, cursor, colsrc, E);

    const float invN = 1.0f / (float)N;
    // 391 m-panels padded to 392 (multiple of 8) -> 392*4 blocks, 1D swizzled grid
    const int Gm = ((N + GBM - 1) / GBM + 7) & ~7;
    const int gemm_blocks = Gm * 4;
    const int uchunk = (N + 199) / 200;
    const int total8 = N * DIM / 8;

    for (int l = 0; l < NLAYERS; l++) {
        float* st1 = stats + (size_t)l * 3 * 1024;
        float* st2 = st1 + 1024;
        float* st3 = st2 + 1024;
        if (l == 0)
            agg_kernel<0><<<N, 128, 0, stream>>>(x, rowptr, colsrc,
                                                 nullptr, nullptr, nullptr, nullptr,
                                                 Phi, Plo, N);
        else
            agg_kernel<1><<<N, 128, 0, stream>>>(Yout, rowptr, colsrc,
                                                 pa2, pc2, pa3, pc3, Phi, Plo, N);
        gemm_kernel<<<gemm_blocks, 256, 0, stream>>>(Phi, Plo,
            Whi + (size_t)(l * 2) * DIM * DIM, Wlo + (size_t)(l * 2) * DIM * DIM,
            b1 + l * DIM, y1, st1, st1 + 512, N);
        params_kernel<<<1, 512, 0, stream>>>(st1, st1 + 512, g1 + l * DIM, be1 + l * DIM,
                                             pa1, pc1, invN);
        convert_kernel<<<2048, 256, 0, stream>>>(y1, pa1, pc1, Phi, Plo, total8);
        gemm_kernel<<<gemm_blocks, 256, 0, stream>>>(Phi, Plo,
            Whi + (size_t)(l * 2 + 1) * DIM * DIM, Wlo + (size_t)(l * 2 + 1) * DIM * DIM,
            b2 + l * DIM, Yout, st2, st2 + 512, N);
        params_kernel<<<1, 512, 0, stream>>>(st2, st2 + 512, g2 + l * DIM, be2 + l * DIM,
                                             pa2, pc2, invN);
        if (l < NLAYERS - 1)
            ustats_kernel<1><<<dim3(2, 200), 256, 0, stream>>>(Yout, pa2, pc2,
                                                               st3, st3 + 512, N, uchunk);
        else
            ustats_kernel<0><<<dim3(2, 200), 256, 0, stream>>>(Yout, pa2, pc2,
                                                               st3, st3 + 512, N, uchunk);
        params_kernel<<<1, 512, 0, stream>>>(st3, st3 + 512, ng + l * DIM, nb + l * DIM,
                                             pa3, pc3, invN);
    }
    finalize_kernel<<<2048, 256, 0, stream>>>(Yout, pa2, pc2, pa3, pc3, N * DIM / 4);
}